// Round 1
// baseline (3885.186 us; speedup 1.0000x reference)
//
#include <hip/hip_runtime.h>
#include <stdint.h>

typedef __attribute__((ext_vector_type(8))) short bf16x8;
typedef __attribute__((ext_vector_type(4))) float f32x4;

__device__ __forceinline__ float bf2f(unsigned short u) {
    union { unsigned int u32; float f; } v; v.u32 = ((unsigned int)u) << 16; return v.f;
}
__device__ __forceinline__ unsigned short f2bf(float f) {
    union { float f; unsigned int u32; } v; v.f = f;
    unsigned int r = v.u32 + 0x7FFFu + ((v.u32 >> 16) & 1u);
    return (unsigned short)(r >> 16);
}
__device__ __forceinline__ float sigm(float x) { return 1.f / (1.f + __expf(-x)); }
__device__ __forceinline__ float tanh_fast(float x) {
    float ax = fabsf(x);
    float e = __expf(-2.f * ax);
    float t = (1.f - e) / (1.f + e);
    return copysignf(t, x);
}

// ---------------- fp32 -> bf16 convert (n4 = count of float4 groups) -------------
__global__ void f2bf_kernel(const float* __restrict__ src, unsigned short* __restrict__ dst, int n4) {
    int i = blockIdx.x * blockDim.x + threadIdx.x;
    if (i >= n4) return;
    float4 v = ((const float4*)src)[i];
    ushort4 o;
    o.x = f2bf(v.x); o.y = f2bf(v.y); o.z = f2bf(v.z); o.w = f2bf(v.w);
    ((ushort4*)dst)[i] = o;
}

// ---------------- combined bias: [2048] = fwd(bih+bhh) | rev(bih+bhh) ------------
__global__ void bias_comb_kernel(const float* __restrict__ bif, const float* __restrict__ bhf,
                                 const float* __restrict__ bir, const float* __restrict__ bhr,
                                 float* __restrict__ out) {
    int n = blockIdx.x * blockDim.x + threadIdx.x;
    if (n >= 2048) return;
    out[n] = (n < 1024) ? (bif[n] + bhf[n]) : (bir[n - 1024] + bhr[n - 1024]);
}

// ---------------- GEMM: C[m,n](bf16) = sum_k A[m,k]*B[n,k] + bias[n] -------------
// A: [M,K] bf16 row-major; B: [N,K] bf16 row-major. Tile 128x128, BK=64.
// 4 waves in 2x2; each wave: 64x64 = 4x4 grid of 16x16x32 MFMAs.
__global__ __launch_bounds__(256, 2) void gemm_bt_bias(
    const unsigned short* __restrict__ A, const unsigned short* __restrict__ B,
    const float* __restrict__ bias, unsigned short* __restrict__ C,
    int M, int N, int K) {
    const int bn0 = blockIdx.x * 128;
    const int bm0 = blockIdx.y * 128;
    const int tid = threadIdx.x;
    const int wave = tid >> 6, lane = tid & 63;
    const int ln15 = lane & 15, quad = lane >> 4;
    const int wr = wave >> 1, wc = wave & 1;

    __shared__ __align__(16) unsigned short At[128 * 72];  // stride 72 to break bank conflicts
    __shared__ __align__(16) unsigned short Bt[128 * 72];

    f32x4 acc[4][4] = {};

    for (int ko = 0; ko < K; ko += 64) {
        // stage 128x64 of A and B: 1024 chunks of 16B each, 4 per thread
#pragma unroll
        for (int i = 0; i < 4; ++i) {
            int chunk = tid + i * 256;
            int row = chunk >> 3, cc = chunk & 7;
            *(bf16x8*)&At[row * 72 + cc * 8] = *(const bf16x8*)&A[(size_t)(bm0 + row) * K + ko + cc * 8];
            *(bf16x8*)&Bt[row * 72 + cc * 8] = *(const bf16x8*)&B[(size_t)(bn0 + row) * K + ko + cc * 8];
        }
        __syncthreads();
#pragma unroll
        for (int kk = 0; kk < 2; ++kk) {
            bf16x8 a[4], b[4];
#pragma unroll
            for (int f = 0; f < 4; ++f) {
                a[f] = *(const bf16x8*)&At[(wr * 64 + f * 16 + ln15) * 72 + kk * 32 + quad * 8];
                b[f] = *(const bf16x8*)&Bt[(wc * 64 + f * 16 + ln15) * 72 + kk * 32 + quad * 8];
            }
#pragma unroll
            for (int fi = 0; fi < 4; ++fi)
#pragma unroll
                for (int fj = 0; fj < 4; ++fj)
                    acc[fi][fj] = __builtin_amdgcn_mfma_f32_16x16x32_bf16(a[fi], b[fj], acc[fi][fj], 0, 0, 0);
        }
        __syncthreads();
    }
    // epilogue: add bias, convert, store bf16
#pragma unroll
    for (int fi = 0; fi < 4; ++fi) {
        int row = bm0 + wr * 64 + fi * 16 + quad * 4;
#pragma unroll
        for (int fj = 0; fj < 4; ++fj) {
            int col = bn0 + wc * 64 + fj * 16 + ln15;
            float bv = bias[col];
#pragma unroll
            for (int r = 0; r < 4; ++r)
                C[(size_t)(row + r) * N + col] = f2bf(acc[fi][fj][r] + bv);
        }
    }
}

// ---------------- persistent LSTM scan (one layer, both directions) --------------
// grid = 32 blocks: dir = blockIdx&1 (XCD spread), bg = blockIdx>>1 (16 batch rows).
// Each WG: h in LDS (bf16), c in regs (fp32), loops t=0..159 streaming Whh from L2.
// Wave w owns h-cols [w*64, w*64+64) -> gate cols {g*256 + w*64 + nb*16 + ln15}.
// gates[b,n] = xg[t,b,dir*1024+n] + sum_k h[b,k]*Whh[n,k]
__global__ __launch_bounds__(256, 1) void lstm_scan(
    const unsigned short* __restrict__ xg,      // [T*B, 2048] bf16
    const unsigned short* __restrict__ whh_f,   // [1024,256] bf16
    const unsigned short* __restrict__ whh_r,   // [1024,256] bf16
    unsigned short* __restrict__ out_bf,        // [T,B,512] bf16 (layer0) or null
    float* __restrict__ out_f)                  // [T,B,512] f32 (layer1) or null
{
    const int dir = blockIdx.x & 1;
    const int bg = blockIdx.x >> 1;
    const int m0 = bg * 16;
    const int tid = threadIdx.x;
    const int wave = tid >> 6, lane = tid & 63;
    const int ln15 = lane & 15, quad = lane >> 4;
    const unsigned short* __restrict__ whh = dir ? whh_r : whh_f;

    __shared__ __align__(16) unsigned short hbuf[16 * 264];  // h [batch][k], stride 264 (pad)
    for (int i = tid; i < 16 * 264; i += 256) hbuf[i] = 0;
    __syncthreads();

    // 16 B-operand base pointers: rows (g*256 + wave*64 + nb*16 + ln15), k-offset quad*8
    const unsigned short* bptr[16];
#pragma unroll
    for (int g = 0; g < 4; ++g)
#pragma unroll
        for (int nb = 0; nb < 4; ++nb)
            bptr[g * 4 + nb] = whh + (size_t)((g * 256 + wave * 64 + nb * 16 + ln15) * 256 + quad * 8);

    float c[16];
#pragma unroll
    for (int i = 0; i < 16; ++i) c[i] = 0.f;

    for (int tt = 0; tt < 160; ++tt) {
        const int t = dir ? (159 - tt) : tt;

        // acc init = xg slice (rows quad*4+r, cols per C/D layout)
        const unsigned short* xr = xg + (size_t)(t * 256 + m0) * 2048 + dir * 1024 + wave * 64 + ln15;
        f32x4 acc[16];
#pragma unroll
        for (int g = 0; g < 4; ++g)
#pragma unroll
            for (int nb = 0; nb < 4; ++nb)
#pragma unroll
                for (int r = 0; r < 4; ++r)
                    acc[g * 4 + nb][r] = bf2f(xr[(size_t)(quad * 4 + r) * 2048 + g * 256 + nb * 16]);

        // K loop: 8 steps of 32; double-buffered B fragments streamed from L2
        bf16x8 Bf[2][16];
#pragma unroll
        for (int q = 0; q < 16; ++q) Bf[0][q] = *(const bf16x8*)(bptr[q]);
#pragma unroll
        for (int kb = 0; kb < 8; ++kb) {
            if (kb < 7) {
#pragma unroll
                for (int q = 0; q < 16; ++q)
                    Bf[(kb + 1) & 1][q] = *(const bf16x8*)(bptr[q] + (kb + 1) * 32);
            }
            bf16x8 af = *(const bf16x8*)&hbuf[ln15 * 264 + kb * 32 + quad * 8];
#pragma unroll
            for (int q = 0; q < 16; ++q)
                acc[q] = __builtin_amdgcn_mfma_f32_16x16x32_bf16(af, Bf[kb & 1][q], acc[q], 0, 0, 0);
        }

        // elementwise LSTM cell (fp32)
        float hv[16];
#pragma unroll
        for (int nb = 0; nb < 4; ++nb)
#pragma unroll
            for (int r = 0; r < 4; ++r) {
                int q = nb * 4 + r;
                float iv = sigm(acc[0 * 4 + nb][r]);
                float fv = sigm(acc[1 * 4 + nb][r]);
                float gv = tanh_fast(acc[2 * 4 + nb][r]);
                float ov = sigm(acc[3 * 4 + nb][r]);
                float cn = fv * c[q] + iv * gv;
                c[q] = cn;
                hv[q] = ov * tanh_fast(cn);
            }

        __syncthreads();  // all waves done reading hbuf (A-frags)
        // write h_t to LDS (bf16) + global output
#pragma unroll
        for (int nb = 0; nb < 4; ++nb)
#pragma unroll
            for (int r = 0; r < 4; ++r) {
                int row = quad * 4 + r;
                int col = wave * 64 + nb * 16 + ln15;
                unsigned short hb = f2bf(hv[nb * 4 + r]);
                hbuf[row * 264 + col] = hb;
                size_t oidx = (size_t)(t * 256 + m0 + row) * 512 + dir * 256 + col;
                if (out_f) out_f[oidx] = hv[nb * 4 + r];
                else out_bf[oidx] = hb;
            }
        __syncthreads();  // h_t visible before next step's reads
    }
}

// ---------------- host-side launch -----------------------------------------------
extern "C" void kernel_launch(void* const* d_in, const int* in_sizes, int n_in,
                              void* d_out, int out_size, void* d_ws, size_t ws_size,
                              hipStream_t stream) {
    const float* x = (const float*)d_in[0];
    float* out = (float*)d_out;
    char* ws = (char*)d_ws;

    // workspace layout (bytes, 256-aligned)
    unsigned short* xbf   = (unsigned short*)(ws + 0);            // 40960x512 bf16   = 41,943,040
    unsigned short* wcat0 = (unsigned short*)(ws + 41943040LL);   // 2048x512 bf16    =  2,097,152
    unsigned short* wcat1 = (unsigned short*)(ws + 44040192LL);   // 2048x512 bf16
    unsigned short* whh0f = (unsigned short*)(ws + 46137344LL);   // 4 x 1024x256 bf16
    unsigned short* whh0r = whh0f + 262144;
    unsigned short* whh1f = whh0f + 524288;
    unsigned short* whh1r = whh0f + 786432;
    float* bias0          = (float*)(ws + 48234496LL);            // 2048 f32
    float* bias1          = (float*)(ws + 48242688LL);            // 2048 f32
    unsigned short* xgbuf = (unsigned short*)(ws + 48250880LL);   // 40960x2048 bf16  = 167,772,160
    unsigned short* h0b   = (unsigned short*)(ws + 216023040LL);  // 40960x512 bf16   = 41,943,040
    // total: 257,966,080 bytes

    // ---- prep: converts + bias combine ----
    f2bf_kernel<<<20480, 256, 0, stream>>>(x, xbf, 5242880);
    f2bf_kernel<<<512, 256, 0, stream>>>((const float*)d_in[1], wcat0, 131072);
    f2bf_kernel<<<512, 256, 0, stream>>>((const float*)d_in[5], wcat0 + 524288, 131072);
    f2bf_kernel<<<512, 256, 0, stream>>>((const float*)d_in[9], wcat1, 131072);
    f2bf_kernel<<<512, 256, 0, stream>>>((const float*)d_in[13], wcat1 + 524288, 131072);
    f2bf_kernel<<<256, 256, 0, stream>>>((const float*)d_in[2], whh0f, 65536);
    f2bf_kernel<<<256, 256, 0, stream>>>((const float*)d_in[6], whh0r, 65536);
    f2bf_kernel<<<256, 256, 0, stream>>>((const float*)d_in[10], whh1f, 65536);
    f2bf_kernel<<<256, 256, 0, stream>>>((const float*)d_in[14], whh1r, 65536);
    bias_comb_kernel<<<8, 256, 0, stream>>>((const float*)d_in[3], (const float*)d_in[4],
                                            (const float*)d_in[7], (const float*)d_in[8], bias0);
    bias_comb_kernel<<<8, 256, 0, stream>>>((const float*)d_in[11], (const float*)d_in[12],
                                            (const float*)d_in[15], (const float*)d_in[16], bias1);

    dim3 gg(16, 320);  // N/128 x M/128
    // ---- layer 0 ----
    gemm_bt_bias<<<gg, 256, 0, stream>>>(xbf, wcat0, bias0, xgbuf, 40960, 2048, 512);
    lstm_scan<<<32, 256, 0, stream>>>(xgbuf, whh0f, whh0r, h0b, nullptr);
    // ---- layer 1 ----
    gemm_bt_bias<<<gg, 256, 0, stream>>>(h0b, wcat1, bias1, xgbuf, 40960, 2048, 512);
    lstm_scan<<<32, 256, 0, stream>>>(xgbuf, whh1f, whh1r, nullptr, out);
}